// Round 16
// baseline (265.911 us; speedup 1.0000x reference)
//
#include <hip/hip_runtime.h>
#include <math.h>

// Problem constants (from reference)
#define B_ 4
#define S_ 4096
#define D_ 128
#define N_ 16
#define CHUNK_ 64
#define NCHUNK_ (S_ / CHUNK_)   // 64
#define NTASK_ (B_ * 8 * NCHUNK_) // 2048 blocks
#define NCHAN_ (B_ * D_ * N_)   // 8192
#define KC_ 8                   // kS chunk length
#define KNC_ (S_ / KC_)         // 512 chunks

// Diagnostic repetition factors (idempotent; revert to 1 after capture)
#define K1REP 10
#define KSREP 30
#define K30REP 5
#define K31REP 4

#define CAPF  3.0e38f
#define LOG2E 1.4426950408889634f
#define C70F  100.98865286222744f       // 70 * log2(e)

__device__ __forceinline__ float fast_sp(float z) {
    return fmaxf(z, 0.0f) + __logf(1.0f + __expf(-fabsf(z)));
}

__device__ __forceinline__ float exp2_hw(float x) {
#if __has_builtin(__builtin_amdgcn_exp2f)
    return __builtin_amdgcn_exp2f(x);
#else
    return exp2f(x);
#endif
}

template<int CTRL>
__device__ __forceinline__ float dpp_radd(float v) {
    int o = __builtin_amdgcn_mov_dpp(__float_as_int(v), CTRL, 0xf, 0xf, true);
    return v + __int_as_float(o);
}

__device__ __forceinline__ float dpp_reduce16(float v) {
    v = dpp_radd<0x121>(v);
    v = dpp_radd<0x122>(v);
    v = dpp_radd<0x124>(v);
    v = dpp_radd<0x128>(v);
    return v;
}

// ---------------------------------------------------------------------------
// K1: projections. xWD[b,t]; BmT[b,n,t]; CmT[b,n,t] (coalesced via LDS).
// ---------------------------------------------------------------------------
__global__ __launch_bounds__(256) void k1_proj(
    const float* __restrict__ x,
    const float* __restrict__ W_B, const float* __restrict__ b_B,
    const float* __restrict__ W_C, const float* __restrict__ b_C,
    const float* __restrict__ W_D, const float* __restrict__ b_D,
    float* __restrict__ xWD, float* __restrict__ BmT, float* __restrict__ CmT)
{
    __shared__ float xs[16][132];
    __shared__ float sB[16][17], sC[16][17];
    const int row0 = blockIdx.x * 16;
    const int b  = row0 >> 12;
    const int t0 = row0 & (S_ - 1);
    const int tid = threadIdx.x;

    for (int rep = 0; rep < K1REP; ++rep) {
        {
            const float4* xsrc = (const float4*)(x + (size_t)row0 * D_);
            int i0 = tid * 2;
            float4 v0 = xsrc[i0];
            float4 v1 = xsrc[i0 + 1];
            int r = i0 >> 5;
            int c = (i0 << 2) & 127;
            *(float4*)&xs[r][c]     = v0;
            *(float4*)&xs[r][c + 4] = v1;
        }
        __syncthreads();

        const int r = tid >> 4;
        const int n = tid & 15;
        float a = 0.f, c = 0.f;
        #pragma unroll 4
        for (int k = 0; k < D_; ++k) {
            float xv = xs[r][k];
            a = fmaf(xv, W_B[k * N_ + n], a);
            c = fmaf(xv, W_C[k * N_ + n], c);
        }
        sB[n][r] = a + b_B[n];
        sC[n][r] = c + b_C[n];

        if (tid < 16) {
            float dsum = 0.f;
            #pragma unroll 4
            for (int k = 0; k < D_; ++k) dsum = fmaf(xs[tid][k], W_D[k], dsum);
            xWD[row0 + tid] = dsum + b_D[0];
        }
        __syncthreads();

        const int n2 = tid >> 4, r2 = tid & 15;
        BmT[(size_t)(b * N_ + n2) * S_ + t0 + r2] = sB[n2][r2];
        CmT[(size_t)(b * N_ + n2) * S_ + t0 + r2] = sC[n2][r2];
        __syncthreads();
    }
}

// ---------------------------------------------------------------------------
// KS: fused per-chunk softplus sums + block-scan -> dstart[bd,512].
// ---------------------------------------------------------------------------
__global__ __launch_bounds__(512) void kS(
    const float* __restrict__ xWD, const float* __restrict__ P,
    float* __restrict__ dstart)
{
    __shared__ float wtot[8];
    const int bd = blockIdx.x;
    const int b = bd >> 7, d = bd & (D_ - 1);
    const float Pd = P[d];
    const int c = threadIdx.x;
    const int lane = c & 63, wv = c >> 6;

    for (int rep = 0; rep < KSREP; ++rep) {
        const float4* xw = (const float4*)(xWD + b * S_) + c * 2;
        float4 a0 = xw[0], a1 = xw[1];
        float s = fast_sp(Pd + a0.x) + fast_sp(Pd + a0.y)
                + fast_sp(Pd + a0.z) + fast_sp(Pd + a0.w)
                + fast_sp(Pd + a1.x) + fast_sp(Pd + a1.y)
                + fast_sp(Pd + a1.z) + fast_sp(Pd + a1.w);
        float sc = s;
        #pragma unroll
        for (int off = 1; off < 64; off <<= 1) {
            float o = __shfl_up(sc, off);
            if (lane >= off) sc += o;
        }
        if (lane == 63) wtot[wv] = sc;
        __syncthreads();
        float base = 0.f;
        #pragma unroll
        for (int i = 0; i < 7; ++i)
            if (i < wv) base += wtot[i];
        dstart[bd * KNC_ + c] = base + sc - s;   // exclusive
        __syncthreads();
    }
}

// ---------------------------------------------------------------------------
// Staging helpers
// ---------------------------------------------------------------------------
__device__ __forceinline__ void stage_x(
    const float* __restrict__ x, float* ld_x,
    int b, int t0, int dg, int lane)
{
    const float* src = x + ((size_t)b * S_ + t0) * D_ + dg * 16;
    #pragma unroll
    for (int it = 0; it < 4; ++it) {
        int g = it * 64 + lane;
        int t = g >> 2, dq = g & 3;
        float4 v = *(const float4*)(src + (size_t)t * D_ + dq * 4);
        int t4 = t >> 2, tl = t & 3;
        const float va[4] = {v.x, v.y, v.z, v.w};
        #pragma unroll
        for (int j = 0; j < 4; ++j) {
            int dd = dq * 4 + j;
            ld_x[dd * 64 + ((t4 ^ (dd & 7)) << 2) + tl] = va[j];
        }
    }
}

__device__ __forceinline__ void stage_rowmajor(
    const float* __restrict__ src, float* dst, int lane)
{
    #pragma unroll
    for (int it = 0; it < 4; ++it) {
        int g = it * 64 + lane;
        int row = g >> 4, t16 = g & 15;
        int tlog = t16 ^ (row & 7);
        *(float4*)&dst[row * 64 + t16 * 4] =
            *(const float4*)(src + (size_t)row * S_ + tlog * 4);
    }
}

__device__ __forceinline__ void stage_disc(
    const float* __restrict__ xWD, const float* __restrict__ P,
    float* ld_d, int b, int t0, int dg, int lane)
{
    float v = xWD[b * S_ + t0 + lane];
    int t4 = lane >> 2, tl = lane & 3;
    #pragma unroll
    for (int dl2 = 0; dl2 < 16; ++dl2) {
        float sp = fast_sp(P[dg * 16 + dl2] + v);
        ld_d[dl2 * 64 + ((t4 ^ (dl2 & 7)) << 2) + tl] = sp;
    }
}

// ---------------------------------------------------------------------------
// K3: LDS-staged chunked scan (r15 logic, REP-wrapped for visibility).
// ---------------------------------------------------------------------------
template <int PHASE_C>
__global__ __launch_bounds__(256, 8) void k3_scan(
    const float* __restrict__ x, const float* __restrict__ Araw,
    const float* __restrict__ P, const float* __restrict__ xWD,
    const float* __restrict__ BmT, const float* __restrict__ CmT,
    const float* __restrict__ dstart,
    float* __restrict__ csum,
    float* __restrict__ y)
{
    __shared__ __align__(16) float lds[PHASE_C ? 5 * 1024 : 3 * 1024 + 64];
    __shared__ int wflags[4];
    float* ld_x = lds;
    float* ld_b = lds + 1024;
    float* ld_d = lds + 2048;
    float* ld_c = lds + (PHASE_C ? 3072 : 0);
    float* ld_y = lds + (PHASE_C ? 4096 : 0);

    const int blk = blockIdx.x;
    const int dg = blk & 7;
    const int ch = (blk >> 3) & (NCHUNK_ - 1);
    const int b  = blk >> 9;
    const int tid = threadIdx.x;
    const int lane = tid & 63;
    const int w = tid >> 6;
    const int n  = tid & 15;
    const int dl = tid >> 4;
    const int d  = dg * 16 + dl;
    const int bd = b * D_ + d;
    const int cid = bd * N_ + n;
    const int t0 = ch * CHUNK_;

    const int NREP = PHASE_C ? K31REP : K30REP;
    for (int rep = 0; rep < NREP; ++rep) {
        // ---- early predicate ----
        const float A  = -fast_sp(Araw[d * N_ + n]);
        const float rA = 1.0f / A;
        const float A2 = A * LOG2E;
        const float cum0 = fmaf(A2, dstart[bd * KNC_ + ch * (CHUNK_ / KC_)], C70F);
        const bool fastp = __all(cum0 <= -128.0f);

        bool blockfast = false;
        if (!PHASE_C) {
            if (lane == 0) wflags[w] = fastp ? 1 : 0;
            __syncthreads();
            blockfast = (wflags[0] & wflags[1] & wflags[2] & wflags[3]) != 0;
        }

        // ---- inline carry (phase C) ----
        float carry = 0.f;
        if (PHASE_C) {
            float p0 = 0.f, p1 = 0.f, p2 = 0.f, p3 = 0.f;
            int k = 0;
            for (; k + 4 <= ch; k += 4) {
                p0 += csum[(size_t)(k + 0) * NCHAN_ + cid];
                p1 += csum[(size_t)(k + 1) * NCHAN_ + cid];
                p2 += csum[(size_t)(k + 2) * NCHAN_ + cid];
                p3 += csum[(size_t)(k + 3) * NCHAN_ + cid];
            }
            for (; k < ch; ++k) p0 += csum[(size_t)k * NCHAN_ + cid];
            carry = (p0 + p1) + (p2 + p3);
        }

        // ---- stage ----
        if (w == 0)      stage_x(x, ld_x, b, t0, dg, lane);
        else if (w == 1) stage_rowmajor(BmT + (size_t)(b * N_) * S_ + t0, ld_b, lane);
        else if (PHASE_C && w == 2)
                         stage_rowmajor(CmT + (size_t)(b * N_) * S_ + t0, ld_c, lane);
        else if (w == (PHASE_C ? 3 : 2)) {
            if (PHASE_C || !blockfast)
                stage_disc(xWD, P, ld_d, b, t0, dg, lane);
        }
        __syncthreads();

        if (!PHASE_C) {
            unsigned long long* mk = (unsigned long long*)(lds + 3072);
            #pragma unroll
            for (int i = 0; i < 4; ++i) {
                int rr = w * 4 + i;
                int idx = rr * 64 + ((((lane >> 2) ^ (rr & 7)) << 2) | (lane & 3));
                unsigned long long mx = __ballot((__float_as_uint(ld_x[idx]) >> 31) & 1);
                unsigned long long mb = __ballot((__float_as_uint(ld_b[idx]) >> 31) & 1);
                if (lane == 0) { mk[rr] = mx; mk[16 + rr] = mb; }
            }
            __syncthreads();
        }

        float cum2 = cum0;
        float run = carry;

        const int sdl = dl & 7, sn = n & 7;
        const int offd_base = dl * 64;
        const int offn_base = n * 64;

        if (fastp) {
            if (!PHASE_C) {
                const unsigned long long* mk =
                    (const unsigned long long*)(lds + 3072);
                int pc = (int)__popcll(mk[dl] ^ mk[16 + n]);
                run += (float)(64 - 2 * pc);
            } else {
                #pragma unroll 2
                for (int t4 = 0; t4 < CHUNK_ / 4; ++t4) {
                    const int od = offd_base + ((t4 ^ sdl) << 2);
                    const int on = offn_base + ((t4 ^ sn) << 2);
                    float4 dv = *(const float4*)&ld_d[od];
                    float4 xv = *(const float4*)&ld_x[od];
                    float4 bv = *(const float4*)&ld_b[on];
                    float4 Cv = *(const float4*)&ld_c[on];
                    const float dva[4] = {dv.x, dv.y, dv.z, dv.w};
                    const float xva[4] = {xv.x, xv.y, xv.z, xv.w};
                    const float bva[4] = {bv.x, bv.y, bv.z, bv.w};
                    const float Cva[4] = {Cv.x, Cv.y, Cv.z, Cv.w};
                    #pragma unroll
                    for (int j = 0; j < 4; ++j) {
                        float ab  = exp2_hw(dva[j] * A2);
                        float ww  = fmaf(ab, xva[j], -xva[j]);
                        float Bx  = (bva[j] * rA) * ww;
                        run += copysignf(1.0f, Bx);
                        float yv = run * fabsf(Bx) * Cva[j];
                        yv = dpp_reduce16(yv);
                        if (n == 0) ld_y[(t4 * 4 + j) * 16 + dl] = yv;
                    }
                }
            }
        } else {
            #pragma unroll 2
            for (int t4 = 0; t4 < CHUNK_ / 4; ++t4) {
                const int od = offd_base + ((t4 ^ sdl) << 2);
                const int on = offn_base + ((t4 ^ sn) << 2);
                float4 dv = *(const float4*)&ld_d[od];
                float4 xv = *(const float4*)&ld_x[od];
                float4 bv = *(const float4*)&ld_b[on];
                float4 Cv;
                if (PHASE_C) Cv = *(const float4*)&ld_c[on];
                const float dva[4] = {dv.x, dv.y, dv.z, dv.w};
                const float xva[4] = {xv.x, xv.y, xv.z, xv.w};
                const float bva[4] = {bv.x, bv.y, bv.z, bv.w};
                const float Cva[4] = {Cv.x, Cv.y, Cv.z, Cv.w};
                #pragma unroll
                for (int j = 0; j < 4; ++j) {
                    float t1 = dva[j] * A2;
                    cum2 += t1;
                    float ab  = exp2_hw(t1);
                    float ww  = fmaf(ab, xva[j], -xva[j]);
                    float Bx  = (bva[j] * rA) * ww;
                    float aBx = fabsf(Bx);
                    float en  = fminf(exp2_hw(-cum2), CAPF);
                    float m   = aBx * en;
                    float mag = fminf(m, 1.0f);
                    run += copysignf(mag, Bx);
                    if (PHASE_C) {
                        float ecl = aBx * __builtin_amdgcn_rcpf(fmaxf(mag, 1e-37f));
                        float yv = run * ecl * Cva[j];
                        yv = dpp_reduce16(yv);
                        if (n == 0) ld_y[(t4 * 4 + j) * 16 + dl] = yv;
                    }
                }
            }
        }

        if (!PHASE_C) {
            csum[(size_t)ch * NCHAN_ + cid] = run;
        } else {
            __syncthreads();
            int t  = tid >> 2;
            int dp = tid & 3;
            float4 v = *(const float4*)&ld_y[t * 16 + dp * 4];
            *(float4*)&y[((size_t)b * S_ + t0 + t) * D_ + dg * 16 + dp * 4] = v;
        }
        __syncthreads();
    }
}

// ---------------------------------------------------------------------------
extern "C" void kernel_launch(void* const* d_in, const int* in_sizes, int n_in,
                              void* d_out, int out_size, void* d_ws, size_t ws_size,
                              hipStream_t stream)
{
    const float* x    = (const float*)d_in[0];
    const float* Araw = (const float*)d_in[1];
    const float* P    = (const float*)d_in[2];
    const float* W_B  = (const float*)d_in[3];
    const float* b_B  = (const float*)d_in[4];
    const float* W_C  = (const float*)d_in[5];
    const float* b_C  = (const float*)d_in[6];
    const float* W_D  = (const float*)d_in[7];
    const float* b_D  = (const float*)d_in[8];
    float* y  = (float*)d_out;
    float* ws = (float*)d_ws;

    float* xWD    = ws;                                    // 16384
    float* BmT    = xWD  + B_ * S_;                        // 262144
    float* CmT    = BmT  + B_ * S_ * N_;                   // 262144
    float* dstart = CmT  + B_ * S_ * N_;                   // 262144
    float* csum   = dstart + B_ * D_ * KNC_;               // 524288

    hipLaunchKernelGGL(k1_proj, dim3(B_ * S_ / 16), dim3(256), 0, stream,
                       x, W_B, b_B, W_C, b_C, W_D, b_D, xWD, BmT, CmT);
    hipLaunchKernelGGL(kS, dim3(B_ * D_), dim3(512), 0, stream,
                       xWD, P, dstart);
    hipLaunchKernelGGL((k3_scan<0>), dim3(NTASK_), dim3(256), 0, stream,
                       x, Araw, P, xWD, BmT, CmT, dstart, csum, y);
    hipLaunchKernelGGL((k3_scan<1>), dim3(NTASK_), dim3(256), 0, stream,
                       x, Araw, P, xWD, BmT, CmT, dstart, csum, y);
}

// Round 17
// 55.117 us; speedup vs baseline: 4.8245x; 4.8245x over previous
//
#include <hip/hip_runtime.h>
#include <math.h>

// Problem constants (from reference)
#define B_ 4
#define S_ 4096
#define D_ 128
#define N_ 16
#define CHUNK_ 64
#define NCHUNK_ (S_ / CHUNK_)   // 64
#define NTASK_ (B_ * 8 * NCHUNK_) // 2048 blocks
#define NCHAN_ (B_ * D_ * N_)   // 8192
#define KC_ 8                   // kS chunk length
#define KNC_ (S_ / KC_)         // 512 chunks

#define CAPF  3.0e38f
#define LOG2E 1.4426950408889634f
#define C70F  100.98865286222744f       // 70 * log2(e)

__device__ __forceinline__ float fast_sp(float z) {
    return fmaxf(z, 0.0f) + __logf(1.0f + __expf(-fabsf(z)));
}

__device__ __forceinline__ float exp2_hw(float x) {
#if __has_builtin(__builtin_amdgcn_exp2f)
    return __builtin_amdgcn_exp2f(x);
#else
    return exp2f(x);
#endif
}

template<int CTRL>
__device__ __forceinline__ float dpp_radd(float v) {
    int o = __builtin_amdgcn_mov_dpp(__float_as_int(v), CTRL, 0xf, 0xf, true);
    return v + __int_as_float(o);
}

__device__ __forceinline__ float dpp_reduce16(float v) {
    v = dpp_radd<0x121>(v);
    v = dpp_radd<0x122>(v);
    v = dpp_radd<0x124>(v);
    v = dpp_radd<0x128>(v);
    return v;
}

// ---------------------------------------------------------------------------
// K1: projections. W_B/W_C transposed into LDS once per block; dot products
// are float4 LDS reads with dual accumulators (was: 256 scalar global loads).
// ---------------------------------------------------------------------------
__global__ __launch_bounds__(256) void k1_proj(
    const float* __restrict__ x,
    const float* __restrict__ W_B, const float* __restrict__ b_B,
    const float* __restrict__ W_C, const float* __restrict__ b_C,
    const float* __restrict__ W_D, const float* __restrict__ b_D,
    float* __restrict__ xWD, float* __restrict__ BmT, float* __restrict__ CmT)
{
    __shared__ float xs[16][132];
    __shared__ float wB[16][132];   // [n][k], padded
    __shared__ float wC[16][132];
    __shared__ float sB[16][17], sC[16][17];
    const int row0 = blockIdx.x * 16;
    const int b  = row0 >> 12;
    const int t0 = row0 & (S_ - 1);
    const int tid = threadIdx.x;

    {
        const float4* xsrc = (const float4*)(x + (size_t)row0 * D_);
        int i0 = tid * 2;
        float4 v0 = xsrc[i0];
        float4 v1 = xsrc[i0 + 1];
        int r = i0 >> 5;
        int c = (i0 << 2) & 127;
        *(float4*)&xs[r][c]     = v0;
        *(float4*)&xs[r][c + 4] = v1;

        // W transpose: 2048 floats each = 512 float4; 2 float4/thread
        #pragma unroll
        for (int h = 0; h < 2; ++h) {
            int f = tid + h * 256;
            float4 wb = ((const float4*)W_B)[f];
            float4 wc = ((const float4*)W_C)[f];
            const float wba[4] = {wb.x, wb.y, wb.z, wb.w};
            const float wca[4] = {wc.x, wc.y, wc.z, wc.w};
            int e = f * 4;
            #pragma unroll
            for (int j = 0; j < 4; ++j) {
                int k = (e + j) >> 4, n = (e + j) & 15;
                wB[n][k] = wba[j];
                wC[n][k] = wca[j];
            }
        }
    }
    __syncthreads();

    const int r = tid >> 4;
    const int n = tid & 15;
    float a0 = 0.f, a1 = 0.f, c0 = 0.f, c1 = 0.f;
    #pragma unroll
    for (int k = 0; k < D_; k += 8) {
        float4 xv0 = *(const float4*)&xs[r][k];
        float4 xv1 = *(const float4*)&xs[r][k + 4];
        float4 wb0 = *(const float4*)&wB[n][k];
        float4 wb1 = *(const float4*)&wB[n][k + 4];
        float4 wc0 = *(const float4*)&wC[n][k];
        float4 wc1 = *(const float4*)&wC[n][k + 4];
        a0 = fmaf(xv0.x, wb0.x, a0); a0 = fmaf(xv0.y, wb0.y, a0);
        a0 = fmaf(xv0.z, wb0.z, a0); a0 = fmaf(xv0.w, wb0.w, a0);
        a1 = fmaf(xv1.x, wb1.x, a1); a1 = fmaf(xv1.y, wb1.y, a1);
        a1 = fmaf(xv1.z, wb1.z, a1); a1 = fmaf(xv1.w, wb1.w, a1);
        c0 = fmaf(xv0.x, wc0.x, c0); c0 = fmaf(xv0.y, wc0.y, c0);
        c0 = fmaf(xv0.z, wc0.z, c0); c0 = fmaf(xv0.w, wc0.w, c0);
        c1 = fmaf(xv1.x, wc1.x, c1); c1 = fmaf(xv1.y, wc1.y, c1);
        c1 = fmaf(xv1.z, wc1.z, c1); c1 = fmaf(xv1.w, wc1.w, c1);
    }
    sB[n][r] = (a0 + a1) + b_B[n];
    sC[n][r] = (c0 + c1) + b_C[n];

    if (tid < 16) {
        float dsum = 0.f;
        #pragma unroll 4
        for (int k = 0; k < D_; ++k) dsum = fmaf(xs[tid][k], W_D[k], dsum);
        xWD[row0 + tid] = dsum + b_D[0];
    }
    __syncthreads();

    const int n2 = tid >> 4, r2 = tid & 15;
    BmT[(size_t)(b * N_ + n2) * S_ + t0 + r2] = sB[n2][r2];
    CmT[(size_t)(b * N_ + n2) * S_ + t0 + r2] = sC[n2][r2];
}

// ---------------------------------------------------------------------------
// KS: fused per-chunk softplus sums + block-scan -> dstart[bd,512].
// ---------------------------------------------------------------------------
__global__ __launch_bounds__(512) void kS(
    const float* __restrict__ xWD, const float* __restrict__ P,
    float* __restrict__ dstart)
{
    __shared__ float wtot[8];
    const int bd = blockIdx.x;
    const int b = bd >> 7, d = bd & (D_ - 1);
    const float Pd = P[d];
    const int c = threadIdx.x;
    const int lane = c & 63, wv = c >> 6;

    const float4* xw = (const float4*)(xWD + b * S_) + c * 2;
    float4 a0 = xw[0], a1 = xw[1];
    float s = fast_sp(Pd + a0.x) + fast_sp(Pd + a0.y)
            + fast_sp(Pd + a0.z) + fast_sp(Pd + a0.w)
            + fast_sp(Pd + a1.x) + fast_sp(Pd + a1.y)
            + fast_sp(Pd + a1.z) + fast_sp(Pd + a1.w);
    float sc = s;
    #pragma unroll
    for (int off = 1; off < 64; off <<= 1) {
        float o = __shfl_up(sc, off);
        if (lane >= off) sc += o;
    }
    if (lane == 63) wtot[wv] = sc;
    __syncthreads();
    float base = 0.f;
    #pragma unroll
    for (int i = 0; i < 7; ++i)
        if (i < wv) base += wtot[i];
    dstart[bd * KNC_ + c] = base + sc - s;   // exclusive
}

// ---------------------------------------------------------------------------
// Staging helpers
// ---------------------------------------------------------------------------
__device__ __forceinline__ void stage_x(
    const float* __restrict__ x, float* ld_x,
    int b, int t0, int dg, int lane)
{
    const float* src = x + ((size_t)b * S_ + t0) * D_ + dg * 16;
    #pragma unroll
    for (int it = 0; it < 4; ++it) {
        int g = it * 64 + lane;
        int t = g >> 2, dq = g & 3;
        float4 v = *(const float4*)(src + (size_t)t * D_ + dq * 4);
        int t4 = t >> 2, tl = t & 3;
        const float va[4] = {v.x, v.y, v.z, v.w};
        #pragma unroll
        for (int j = 0; j < 4; ++j) {
            int dd = dq * 4 + j;
            ld_x[dd * 64 + ((t4 ^ (dd & 7)) << 2) + tl] = va[j];
        }
    }
}

__device__ __forceinline__ void stage_rowmajor(
    const float* __restrict__ src, float* dst, int lane)
{
    #pragma unroll
    for (int it = 0; it < 4; ++it) {
        int g = it * 64 + lane;
        int row = g >> 4, t16 = g & 15;
        int tlog = t16 ^ (row & 7);
        *(float4*)&dst[row * 64 + t16 * 4] =
            *(const float4*)(src + (size_t)row * S_ + tlog * 4);
    }
}

__device__ __forceinline__ void stage_disc(
    const float* __restrict__ xWD, const float* __restrict__ P,
    float* ld_d, int b, int t0, int dg, int lane)
{
    float v = xWD[b * S_ + t0 + lane];
    int t4 = lane >> 2, tl = lane & 3;
    #pragma unroll
    for (int dl2 = 0; dl2 < 16; ++dl2) {
        float sp = fast_sp(P[dg * 16 + dl2] + v);
        ld_d[dl2 * 64 + ((t4 ^ (dl2 & 7)) << 2) + tl] = sp;
    }
}

// ---------------------------------------------------------------------------
// K3: LDS-staged chunked scan (r12 mapping). Chunk id relabeled with an
// anti-symmetric pairing: a CU's co-resident blocks (stride-256 apart ->
// chr and chr+32) now handle chunks {c, 63-c}, pairing slow with fast.
// ---------------------------------------------------------------------------
template <int PHASE_C>
__global__ __launch_bounds__(256, 8) void k3_scan(
    const float* __restrict__ x, const float* __restrict__ Araw,
    const float* __restrict__ P, const float* __restrict__ xWD,
    const float* __restrict__ BmT, const float* __restrict__ CmT,
    const float* __restrict__ dstart,
    float* __restrict__ csum,
    float* __restrict__ y)
{
    __shared__ __align__(16) float lds[PHASE_C ? 5 * 1024 : 3 * 1024 + 64];
    __shared__ int wflags[4];
    float* ld_x = lds;
    float* ld_b = lds + 1024;
    float* ld_d = lds + 2048;
    float* ld_c = lds + (PHASE_C ? 3072 : 0);
    float* ld_y = lds + (PHASE_C ? 4096 : 0);

    const int blk = blockIdx.x;
    const int dg = blk & 7;
    const int chr = (blk >> 3) & (NCHUNK_ - 1);
    const int ch = (chr & 32) ? (95 - chr) : chr;   // load-balance pairing
    const int b  = blk >> 9;
    const int tid = threadIdx.x;
    const int lane = tid & 63;
    const int w = tid >> 6;
    const int n  = tid & 15;
    const int dl = tid >> 4;
    const int d  = dg * 16 + dl;
    const int bd = b * D_ + d;
    const int cid = bd * N_ + n;
    const int t0 = ch * CHUNK_;

    // ---- early predicate ----
    const float A  = -fast_sp(Araw[d * N_ + n]);
    const float rA = 1.0f / A;
    const float A2 = A * LOG2E;
    const float cum0 = fmaf(A2, dstart[bd * KNC_ + ch * (CHUNK_ / KC_)], C70F);
    const bool fastp = __all(cum0 <= -128.0f);

    bool blockfast = false;
    if (!PHASE_C) {
        if (lane == 0) wflags[w] = fastp ? 1 : 0;
        __syncthreads();
        blockfast = (wflags[0] & wflags[1] & wflags[2] & wflags[3]) != 0;
    }

    // ---- inline carry (phase C) ----
    float carry = 0.f;
    if (PHASE_C) {
        float p0 = 0.f, p1 = 0.f, p2 = 0.f, p3 = 0.f;
        int k = 0;
        for (; k + 4 <= ch; k += 4) {
            p0 += csum[(size_t)(k + 0) * NCHAN_ + cid];
            p1 += csum[(size_t)(k + 1) * NCHAN_ + cid];
            p2 += csum[(size_t)(k + 2) * NCHAN_ + cid];
            p3 += csum[(size_t)(k + 3) * NCHAN_ + cid];
        }
        for (; k < ch; ++k) p0 += csum[(size_t)k * NCHAN_ + cid];
        carry = (p0 + p1) + (p2 + p3);
    }

    // ---- stage ----
    if (w == 0)      stage_x(x, ld_x, b, t0, dg, lane);
    else if (w == 1) stage_rowmajor(BmT + (size_t)(b * N_) * S_ + t0, ld_b, lane);
    else if (PHASE_C && w == 2)
                     stage_rowmajor(CmT + (size_t)(b * N_) * S_ + t0, ld_c, lane);
    else if (w == (PHASE_C ? 3 : 2)) {
        if (PHASE_C || !blockfast)
            stage_disc(xWD, P, ld_d, b, t0, dg, lane);
    }
    __syncthreads();

    if (!PHASE_C) {
        unsigned long long* mk = (unsigned long long*)(lds + 3072);
        #pragma unroll
        for (int i = 0; i < 4; ++i) {
            int rr = w * 4 + i;
            int idx = rr * 64 + ((((lane >> 2) ^ (rr & 7)) << 2) | (lane & 3));
            unsigned long long mx = __ballot((__float_as_uint(ld_x[idx]) >> 31) & 1);
            unsigned long long mb = __ballot((__float_as_uint(ld_b[idx]) >> 31) & 1);
            if (lane == 0) { mk[rr] = mx; mk[16 + rr] = mb; }
        }
        __syncthreads();
    }

    float cum2 = cum0;
    float run = carry;

    const int sdl = dl & 7, sn = n & 7;
    const int offd_base = dl * 64;
    const int offn_base = n * 64;

    if (fastp) {
        if (!PHASE_C) {
            const unsigned long long* mk =
                (const unsigned long long*)(lds + 3072);
            int pc = (int)__popcll(mk[dl] ^ mk[16 + n]);
            run += (float)(64 - 2 * pc);
        } else {
            #pragma unroll 2
            for (int t4 = 0; t4 < CHUNK_ / 4; ++t4) {
                const int od = offd_base + ((t4 ^ sdl) << 2);
                const int on = offn_base + ((t4 ^ sn) << 2);
                float4 dv = *(const float4*)&ld_d[od];
                float4 xv = *(const float4*)&ld_x[od];
                float4 bv = *(const float4*)&ld_b[on];
                float4 Cv = *(const float4*)&ld_c[on];
                const float dva[4] = {dv.x, dv.y, dv.z, dv.w};
                const float xva[4] = {xv.x, xv.y, xv.z, xv.w};
                const float bva[4] = {bv.x, bv.y, bv.z, bv.w};
                const float Cva[4] = {Cv.x, Cv.y, Cv.z, Cv.w};
                #pragma unroll
                for (int j = 0; j < 4; ++j) {
                    float ab  = exp2_hw(dva[j] * A2);
                    float ww  = fmaf(ab, xva[j], -xva[j]);
                    float Bx  = (bva[j] * rA) * ww;
                    run += copysignf(1.0f, Bx);
                    float yv = run * fabsf(Bx) * Cva[j];
                    yv = dpp_reduce16(yv);
                    if (n == 0) ld_y[(t4 * 4 + j) * 16 + dl] = yv;
                }
            }
        }
    } else {
        #pragma unroll 2
        for (int t4 = 0; t4 < CHUNK_ / 4; ++t4) {
            const int od = offd_base + ((t4 ^ sdl) << 2);
            const int on = offn_base + ((t4 ^ sn) << 2);
            float4 dv = *(const float4*)&ld_d[od];
            float4 xv = *(const float4*)&ld_x[od];
            float4 bv = *(const float4*)&ld_b[on];
            float4 Cv;
            if (PHASE_C) Cv = *(const float4*)&ld_c[on];
            const float dva[4] = {dv.x, dv.y, dv.z, dv.w};
            const float xva[4] = {xv.x, xv.y, xv.z, xv.w};
            const float bva[4] = {bv.x, bv.y, bv.z, bv.w};
            const float Cva[4] = {Cv.x, Cv.y, Cv.z, Cv.w};
            #pragma unroll
            for (int j = 0; j < 4; ++j) {
                float t1 = dva[j] * A2;
                cum2 += t1;
                float ab  = exp2_hw(t1);
                float ww  = fmaf(ab, xva[j], -xva[j]);
                float Bx  = (bva[j] * rA) * ww;
                float aBx = fabsf(Bx);
                float en  = fminf(exp2_hw(-cum2), CAPF);
                float m   = aBx * en;
                float mag = fminf(m, 1.0f);
                run += copysignf(mag, Bx);
                if (PHASE_C) {
                    float ecl = aBx * __builtin_amdgcn_rcpf(fmaxf(mag, 1e-37f));
                    float yv = run * ecl * Cva[j];
                    yv = dpp_reduce16(yv);
                    if (n == 0) ld_y[(t4 * 4 + j) * 16 + dl] = yv;
                }
            }
        }
    }

    if (!PHASE_C) {
        csum[(size_t)ch * NCHAN_ + cid] = run;
    } else {
        __syncthreads();
        int t  = tid >> 2;
        int dp = tid & 3;
        float4 v = *(const float4*)&ld_y[t * 16 + dp * 4];
        *(float4*)&y[((size_t)b * S_ + t0 + t) * D_ + dg * 16 + dp * 4] = v;
    }
}

// ---------------------------------------------------------------------------
extern "C" void kernel_launch(void* const* d_in, const int* in_sizes, int n_in,
                              void* d_out, int out_size, void* d_ws, size_t ws_size,
                              hipStream_t stream)
{
    const float* x    = (const float*)d_in[0];
    const float* Araw = (const float*)d_in[1];
    const float* P    = (const float*)d_in[2];
    const float* W_B  = (const float*)d_in[3];
    const float* b_B  = (const float*)d_in[4];
    const float* W_C  = (const float*)d_in[5];
    const float* b_C  = (const float*)d_in[6];
    const float* W_D  = (const float*)d_in[7];
    const float* b_D  = (const float*)d_in[8];
    float* y  = (float*)d_out;
    float* ws = (float*)d_ws;

    float* xWD    = ws;                                    // 16384
    float* BmT    = xWD  + B_ * S_;                        // 262144
    float* CmT    = BmT  + B_ * S_ * N_;                   // 262144
    float* dstart = CmT  + B_ * S_ * N_;                   // 262144
    float* csum   = dstart + B_ * D_ * KNC_;               // 524288

    hipLaunchKernelGGL(k1_proj, dim3(B_ * S_ / 16), dim3(256), 0, stream,
                       x, W_B, b_B, W_C, b_C, W_D, b_D, xWD, BmT, CmT);
    hipLaunchKernelGGL(kS, dim3(B_ * D_), dim3(512), 0, stream,
                       xWD, P, dstart);
    hipLaunchKernelGGL((k3_scan<0>), dim3(NTASK_), dim3(256), 0, stream,
                       x, Araw, P, xWD, BmT, CmT, dstart, csum, y);
    hipLaunchKernelGGL((k3_scan<1>), dim3(NTASK_), dim3(256), 0, stream,
                       x, Araw, P, xWD, BmT, CmT, dstart, csum, y);
}